// Round 14
// baseline (218848.120 us; speedup 1.0000x reference)
//
#include <hip/hip_runtime.h>

// ---- problem constants ----
constexpr int SQ = 8192;   // sequence length
constexpr int HD = 256;    // hidden size H
constexpr int NG = 1024;   // 4H (gate width)

typedef __fp16 h2 __attribute__((ext_vector_type(2)));
typedef unsigned int uint;
typedef unsigned short ushort;

__device__ __forceinline__ float sigm_f(float x) {
  float e = __builtin_amdgcn_exp2f(-1.4426950408889634f * x);
  return __builtin_amdgcn_rcpf(1.0f + e);
}
__device__ __forceinline__ float tanh_f(float x) {
  float e = __builtin_amdgcn_exp2f(2.885390081777927f * x);
  return 1.0f - 2.0f * __builtin_amdgcn_rcpf(1.0f + e);
}
__device__ __forceinline__ h2 bch2(uint v) { return __builtin_bit_cast(h2, v); }
__device__ __forceinline__ uint pk(float a, float b) {
  return __builtin_bit_cast(uint, __builtin_amdgcn_cvt_pkrtz(a, b));
}
// xor lane-bit-0 exchange via DPP quad_perm [1,0,3,2] — pure VALU
__device__ __forceinline__ float dpp_xor1(float x) {
  int v = __builtin_amdgcn_mov_dpp(__builtin_bit_cast(int, x), 0xB1, 0xF, 0xF, true);
  return __builtin_bit_cast(float, v);
}

// =====================================================================
// xp GEMM: out[d][m][n] = sum_k A[m][k] * W[d][k][n] + bias[d][n]
// =====================================================================
__global__ __launch_bounds__(256) void gemm_xp(const float* __restrict__ A, int K,
                                               const float* __restrict__ W,
                                               const float* __restrict__ bias,
                                               float* __restrict__ out) {
  __shared__ float Al[16][64];  // [k][m]
  __shared__ float Bl[16][64];  // [k][n]
  const int tid = threadIdx.x;
  const int bm = blockIdx.x * 64;
  const int d  = blockIdx.y >> 4;
  const int bn = (blockIdx.y & 15) * 64;
  const float* Wd = W + (size_t)d * K * NG;
  const float* bd = bias + (size_t)d * NG;
  float* outd = out + (size_t)d * SQ * NG;

  const int m4 = (tid >> 4) << 2;
  const int n4 = (tid & 15) << 2;
  const int am = tid >> 2, ak = (tid & 3) << 2;
  const int bk = tid >> 4, bnn = (tid & 15) << 2;

  float acc[4][4] = {};
  for (int kt = 0; kt < K; kt += 16) {
    float4 av = *(const float4*)(A + (size_t)(bm + am) * K + kt + ak);
    float4 bv = *(const float4*)(Wd + (size_t)(kt + bk) * NG + bn + bnn);
    __syncthreads();
    Al[ak + 0][am] = av.x;
    Al[ak + 1][am] = av.y;
    Al[ak + 2][am] = av.z;
    Al[ak + 3][am] = av.w;
    *(float4*)&Bl[bk][bnn] = bv;
    __syncthreads();
#pragma unroll
    for (int k = 0; k < 16; ++k) {
      float4 a = *(const float4*)&Al[k][m4];
      float4 b = *(const float4*)&Bl[k][n4];
      float ar[4] = {a.x, a.y, a.z, a.w};
      float br[4] = {b.x, b.y, b.z, b.w};
#pragma unroll
      for (int i = 0; i < 4; ++i)
#pragma unroll
        for (int jj = 0; jj < 4; ++jj)
          acc[i][jj] = fmaf(ar[i], br[jj], acc[i][jj]);
    }
  }
#pragma unroll
  for (int i = 0; i < 4; ++i) {
    float4 o;
    o.x = acc[i][0] + bd[bn + n4 + 0];
    o.y = acc[i][1] + bd[bn + n4 + 1];
    o.z = acc[i][2] + bd[bn + n4 + 2];
    o.w = acc[i][3] + bd[bn + n4 + 3];
    *(float4*)(outd + (size_t)(bm + m4 + i) * NG + bn + n4) = o;
  }
}

// init: flags[32] (4 fd x 8 waves) and per-layer xcc slates (5 x 16)
__global__ void init_sync(int* flags, int* xcc) {
  const int i = threadIdx.x;
  if (i < 32) flags[i] = 0;
  if (i < 80) xcc[i] = 0;
}

// =====================================================================
// LSTM recurrence v17: 2 same-XCD CUs per direction, K-split.
// 16 blocks launched; each publishes its HW_REG_XCC_ID; all compute the
// SAME deterministic pairing (same-xcd pairs first; >=2 guaranteed by
// pigeonhole over 16 blocks / 8 XCDs). pair0 = fwd, pair1 = bwd; block
// k in pair owns rows [k*128, k*128+128) of W_hh for ALL 1024 cols.
// Thread j: unit u=j>>1, sub-half s=j&1 -> rows [k*128+s*64, +64) for
// the 4 gate cols of u = 32 h2 x 4 = 128 weight VGPRs, ALL architectural
// (no AGPR tax, no LDS weight streaming). Per step per wave:
//   8 h-quad ds_read_b128 (2-addr, free 2-way) -> 128 fdot2 ->
//   DPP xor1 (s-combine) -> even lanes store 4 partials to gx (L2,
//   relaxed agent atomics) -> lane0 release-stores per-WAVE flag ->
//   poll partner wave's flag (acquire) -> load partner partials ->
//   fixed-order sum -> redundant tail (bitwise-identical on both CUs)
//   -> h f16 write to LDS -> one lgkm-only s_barrier.
// xp prefetch issued AFTER the flag release (keeps HBM latency out of
// the release's vmcnt drain). 84KB LDS pad -> 1 block/CU.
// =====================================================================
__global__ __launch_bounds__(512, 1) void lstm_pair(const float* __restrict__ Whh,
                                                    const float* __restrict__ xp,
                                                    float* __restrict__ obuf,
                                                    float* gx, int* flags,
                                                    int* xcc, int ep) {
  __shared__ int  role_sh[2];
  __shared__ uint hl[2][128];      // h f16-packed: dword r = (h[2r],h[2r+1])
  __shared__ uint pad_[21504];     // 84KB occupancy pad -> 1 block/CU

  const int j = threadIdx.x;
  const int w = j >> 6;
  const int l = j & 63;

  // ---- self-organizing same-XCD pairing ----
  if (j == 0) {
    pad_[0] = 0u;
    int myx;
    asm volatile("s_getreg_b32 %0, hwreg(HW_REG_XCC_ID)" : "=s"(myx));
    myx &= 7;
    __hip_atomic_store(&xcc[blockIdx.x], myx + 1, __ATOMIC_RELEASE, __HIP_MEMORY_SCOPE_AGENT);
    int ids[16];
    for (int i = 0; i < 16; ++i) {
      int v;
      do { v = __hip_atomic_load(&xcc[i], __ATOMIC_ACQUIRE, __HIP_MEMORY_SCOPE_AGENT); } while (v == 0);
      ids[i] = v - 1;
    }
    int pa[2][2] = {{-1, -1}, {-1, -1}};
    int np = 0;
    bool used[16];
    for (int i = 0; i < 16; ++i) used[i] = false;
    for (int x = 0; x < 8 && np < 2; ++x) {        // same-xcd pairs, deterministic
      int first = -1;
      for (int i = 0; i < 16 && np < 2; ++i) {
        if (!used[i] && ids[i] == x) {
          if (first < 0) first = i;
          else { pa[np][0] = first; pa[np][1] = i; used[first] = used[i] = true; ++np; first = -1; }
        }
      }
    }
    if (np < 2) {                                   // unreachable (pigeonhole), safety
      int first = -1;
      for (int i = 0; i < 16 && np < 2; ++i) {
        if (!used[i]) {
          if (first < 0) first = i;
          else { pa[np][0] = first; pa[np][1] = i; used[first] = used[i] = true; ++np; first = -1; }
        }
      }
    }
    int rd = -1, rk = 0;
    for (int dd = 0; dd < 2; ++dd)
      for (int kk = 0; kk < 2; ++kk)
        if (pa[dd][kk] == (int)blockIdx.x) { rd = dd; rk = kk; }
    role_sh[0] = rd; role_sh[1] = rk;
  }
  __syncthreads();
  const int d = role_sh[0];
  const int k = role_sh[1];
  if (d < 0) return;

  const int u = j >> 1;              // unit 0..255
  const int s = j & 1;               // 64-row sub-half within this block's K-half
  const float* W   = Whh + (size_t)d * HD * NG;
  const float* xpd = xp + (size_t)d * SQ * NG;
  const int fd_self  = d * 2 + k;
  const int fd_other = d * 2 + (1 - k);
  float* gx_self  = gx + (size_t)fd_self  * 2 * 1024;
  float* gx_other = gx + (size_t)fd_other * 2 * 1024;
  int* flg_self  = flags + fd_self * 8 + w;
  int* flg_other = flags + fd_other * 8 + w;

  // ---- weights: rows [k*128 + s*64, +64) x cols {g*256+u}: 128 arch VGPRs ----
  h2 wr[4][32];
#pragma unroll
  for (int g = 0; g < 4; ++g) {
    const float* Wc = W + (size_t)(k * 128 + s * 64) * NG + g * 256 + u;
#pragma unroll
    for (int m = 0; m < 32; ++m)
      wr[g][m] = __builtin_amdgcn_cvt_pkrtz(Wc[(size_t)(2 * m) * NG],
                                            Wc[(size_t)(2 * m + 1) * NG]);
  }

  if (j < 256) ((uint*)hl)[j] = 0u;
  __syncthreads();

  const int fwd = (d == 0) ? 1 : 0;
  int t = fwd ? 0 : SQ - 1;
  const int dt = fwd ? 1 : -1;
  const int hqbase = k * 16 + s * 8;   // uint4 index into hl[p]
  float cc = 0.0f;
  int p = 0;

  float xc[4], xn[4] = {};
#pragma unroll
  for (int g = 0; g < 4; ++g) xc[g] = xpd[(size_t)t * NG + g * 256 + u];

  for (int step = 0; step < SQ; ++step) {
    // ---- dots over this block's 64-row slice ----
    const uint4* hb = (const uint4*)hl[p];
    float acc[4] = {0.0f, 0.0f, 0.0f, 0.0f};
#pragma unroll
    for (int q = 0; q < 8; ++q) {
      uint4 hq = hb[hqbase + q];
      h2 hx = bch2(hq.x), hy = bch2(hq.y), hz = bch2(hq.z), hw = bch2(hq.w);
#pragma unroll
      for (int g = 0; g < 4; ++g) {
        acc[g] = __builtin_amdgcn_fdot2(wr[g][4 * q + 0], hx, acc[g], false);
        acc[g] = __builtin_amdgcn_fdot2(wr[g][4 * q + 1], hy, acc[g], false);
        acc[g] = __builtin_amdgcn_fdot2(wr[g][4 * q + 2], hz, acc[g], false);
        acc[g] = __builtin_amdgcn_fdot2(wr[g][4 * q + 3], hw, acc[g], false);
      }
    }

    // ---- s-combine (pure VALU): both lanes now hold the K-half partial ----
    float part[4];
#pragma unroll
    for (int g = 0; g < 4; ++g) part[g] = acc[g] + dpp_xor1(acc[g]);

    // ---- publish partials (even lanes), per-wave flag release ----
    float* gxs = gx_self + (size_t)(step & 1) * 1024;
    if (!(j & 1)) {
#pragma unroll
      for (int g = 0; g < 4; ++g)
        __hip_atomic_store(gxs + g * 256 + u, part[g], __ATOMIC_RELAXED,
                           __HIP_MEMORY_SCOPE_AGENT);
    }
    const int target = ep + step + 1;
    if (l == 0)
      __hip_atomic_store(flg_self, target, __ATOMIC_RELEASE, __HIP_MEMORY_SCOPE_AGENT);

    // prefetch next xp AFTER the release (HBM latency hides under poll/tail)
    if (step + 1 < SQ) {
#pragma unroll
      for (int g = 0; g < 4; ++g) xn[g] = xpd[(size_t)(t + dt) * NG + g * 256 + u];
    }

    // ---- wait for partner wave, read its partials ----
    while (__hip_atomic_load(flg_other, __ATOMIC_ACQUIRE, __HIP_MEMORY_SCOPE_AGENT) < target) {}
    const float* gxo = gx_other + (size_t)(step & 1) * 1024;
    float pre[4];
#pragma unroll
    for (int g = 0; g < 4; ++g) {
      float po = __hip_atomic_load(gxo + g * 256 + u, __ATOMIC_RELAXED,
                                   __HIP_MEMORY_SCOPE_AGENT);
      float a = k ? po : part[g];        // fixed order: rows 0-127 first
      float b = k ? part[g] : po;
      pre[g] = a + b + xc[g];
    }

    // ---- redundant tail (bitwise-identical on both CUs of the pair) ----
    float iv = sigm_f(pre[0]);
    float fv = sigm_f(pre[1]);
    float gv = tanh_f(pre[2]);
    float ov = sigm_f(pre[3]);
    cc = fv * cc + iv * gv;
    float hv = ov * tanh_f(cc);

    if (!(j & 1)) {
      if (k == 0) obuf[(size_t)t * 512 + (d << 8) + u] = hv;   // fire-and-forget
      ((ushort*)hl[p ^ 1])[u] = (ushort)(pk(hv, hv) & 0xFFFFu);
    }

    // ---- one raw barrier: LDS ordering only ----
    asm volatile("s_waitcnt lgkmcnt(0)" ::: "memory");
    __builtin_amdgcn_s_barrier();
    __builtin_amdgcn_sched_barrier(0);

    p ^= 1;
#pragma unroll
    for (int g = 0; g < 4; ++g) xc[g] = xn[g];
    t += dt;
  }
}

// =====================================================================
// classifier head
// =====================================================================
__global__ void cls_k(const float* __restrict__ buf, const float* __restrict__ w1,
                      const float* __restrict__ b1, const float* __restrict__ w2,
                      const float* __restrict__ b2, float* __restrict__ out) {
  __shared__ float feat[512];
  __shared__ float hid[32];
  const int t = threadIdx.x;
  feat[t] = (t < 256) ? buf[(size_t)(SQ - 1) * 512 + t] : buf[t];
  __syncthreads();
  if (t < 32) {
    float a = b1[t];
    for (int k = 0; k < 512; ++k) a = fmaf(feat[k], w1[k * 32 + t], a);
    hid[t] = a;
  }
  __syncthreads();
  if (t < 2) {
    float a = b2[t];
    for (int k = 0; k < 32; ++k) a = fmaf(hid[k], w2[k * 2 + t], a);
    out[t] = a;
  }
}

// =====================================================================
extern "C" void kernel_launch(void* const* d_in, const int* in_sizes, int n_in,
                              void* d_out, int out_size, void* d_ws, size_t ws_size,
                              hipStream_t stream) {
  const float* x     = (const float*)d_in[0];
  const float* w_ih0 = (const float*)d_in[1];
  const float* w_hh0 = (const float*)d_in[2];
  const float* b0    = (const float*)d_in[3];
  const float* w_ih  = (const float*)d_in[4];
  const float* w_hh  = (const float*)d_in[5];
  const float* b     = (const float*)d_in[6];
  const float* w1    = (const float*)d_in[7];
  const float* b1    = (const float*)d_in[8];
  const float* w2    = (const float*)d_in[9];
  const float* b2    = (const float*)d_in[10];

  float* xp   = (float*)d_ws;                       // [2][SQ][NG] = 64MB
  float* bufA = xp + (size_t)2 * SQ * NG;           // [SQ][512]   = 16MB
  float* bufB = bufA + (size_t)SQ * 512;            // [SQ][512]   = 16MB
  float* gx   = bufB + (size_t)SQ * 512;            // [4][2][1024] = 32KB
  int*   flags = (int*)(gx + 4 * 2 * 1024);         // [32]
  int*   xcc   = flags + 32;                        // [5][16]

  const dim3 ggrid(SQ / 64, 32);

  init_sync<<<1, 128, 0, stream>>>(flags, xcc);

  // layer 0
  gemm_xp<<<ggrid, 256, 0, stream>>>(x, 1024, w_ih0, b0, xp);
  lstm_pair<<<16, 512, 0, stream>>>(w_hh0, xp, bufA, gx, flags, xcc + 0 * 16, 0 * SQ);

  // layers 1..4
  float* cur = bufA;
  float* nxt = bufB;
  for (int lyr = 0; lyr < 4; ++lyr) {
    gemm_xp<<<ggrid, 256, 0, stream>>>(cur, 512, w_ih + (size_t)lyr * 2 * 512 * 1024,
                                       b + (size_t)lyr * 2 * 1024, xp);
    lstm_pair<<<16, 512, 0, stream>>>(w_hh + (size_t)lyr * 2 * 256 * 1024, xp, nxt,
                                      gx, flags, xcc + (lyr + 1) * 16, (lyr + 1) * SQ);
    float* tmp = cur; cur = nxt; nxt = tmp;
  }

  cls_k<<<1, 512, 0, stream>>>(cur, w1, b1, w2, b2, (float*)d_out);
}

// Round 15
// 71435.760 us; speedup vs baseline: 3.0636x; 3.0636x over previous
//
#include <hip/hip_runtime.h>

// ---- problem constants ----
constexpr int SQ = 8192;   // sequence length
constexpr int HD = 256;    // hidden size H
constexpr int NG = 1024;   // 4H (gate width)

typedef __fp16 h2 __attribute__((ext_vector_type(2)));
typedef unsigned int uint;
typedef unsigned short ushort;

__device__ __forceinline__ float sigm_f(float x) {
  float e = __builtin_amdgcn_exp2f(-1.4426950408889634f * x);
  return __builtin_amdgcn_rcpf(1.0f + e);
}
__device__ __forceinline__ float tanh_f(float x) {
  float e = __builtin_amdgcn_exp2f(2.885390081777927f * x);
  return 1.0f - 2.0f * __builtin_amdgcn_rcpf(1.0f + e);
}
__device__ __forceinline__ h2 bch2(uint v) { return __builtin_bit_cast(h2, v); }
__device__ __forceinline__ uint pk(float a, float b) {
  return __builtin_bit_cast(uint, __builtin_amdgcn_cvt_pkrtz(a, b));
}
// quad_perm DPP exchanges — pure VALU, no DS pipe
__device__ __forceinline__ float dpp_xor1(float x) {  // [1,0,3,2]
  int v = __builtin_amdgcn_mov_dpp(__builtin_bit_cast(int, x), 0xB1, 0xF, 0xF, true);
  return __builtin_bit_cast(float, v);
}
__device__ __forceinline__ float dpp_xor2(float x) {  // [2,3,0,1]
  int v = __builtin_amdgcn_mov_dpp(__builtin_bit_cast(int, x), 0x4E, 0xF, 0xF, true);
  return __builtin_bit_cast(float, v);
}

// =====================================================================
// xp GEMM: out[d][m][n] = sum_k A[m][k] * W[d][k][n] + bias[d][n]
// =====================================================================
__global__ __launch_bounds__(256) void gemm_xp(const float* __restrict__ A, int K,
                                               const float* __restrict__ W,
                                               const float* __restrict__ bias,
                                               float* __restrict__ out) {
  __shared__ float Al[16][64];  // [k][m]
  __shared__ float Bl[16][64];  // [k][n]
  const int tid = threadIdx.x;
  const int bm = blockIdx.x * 64;
  const int d  = blockIdx.y >> 4;
  const int bn = (blockIdx.y & 15) * 64;
  const float* Wd = W + (size_t)d * K * NG;
  const float* bd = bias + (size_t)d * NG;
  float* outd = out + (size_t)d * SQ * NG;

  const int m4 = (tid >> 4) << 2;
  const int n4 = (tid & 15) << 2;
  const int am = tid >> 2, ak = (tid & 3) << 2;
  const int bk = tid >> 4, bnn = (tid & 15) << 2;

  float acc[4][4] = {};
  for (int kt = 0; kt < K; kt += 16) {
    float4 av = *(const float4*)(A + (size_t)(bm + am) * K + kt + ak);
    float4 bv = *(const float4*)(Wd + (size_t)(kt + bk) * NG + bn + bnn);
    __syncthreads();
    Al[ak + 0][am] = av.x;
    Al[ak + 1][am] = av.y;
    Al[ak + 2][am] = av.z;
    Al[ak + 3][am] = av.w;
    *(float4*)&Bl[bk][bnn] = bv;
    __syncthreads();
#pragma unroll
    for (int k = 0; k < 16; ++k) {
      float4 a = *(const float4*)&Al[k][m4];
      float4 b = *(const float4*)&Bl[k][n4];
      float ar[4] = {a.x, a.y, a.z, a.w};
      float br[4] = {b.x, b.y, b.z, b.w};
#pragma unroll
      for (int i = 0; i < 4; ++i)
#pragma unroll
        for (int jj = 0; jj < 4; ++jj)
          acc[i][jj] = fmaf(ar[i], br[jj], acc[i][jj]);
    }
  }
#pragma unroll
  for (int i = 0; i < 4; ++i) {
    float4 o;
    o.x = acc[i][0] + bd[bn + n4 + 0];
    o.y = acc[i][1] + bd[bn + n4 + 1];
    o.z = acc[i][2] + bd[bn + n4 + 2];
    o.w = acc[i][3] + bd[bn + n4 + 3];
    *(float4*)(outd + (size_t)(bm + m4 + i) * NG + bn + n4) = o;
  }
}

// =====================================================================
// LSTM recurrence v19: 4-way K-split unit-pair owner. 1 WG/direction,
// 512 threads (8 waves). Thread (m=j>>2, q=j&3) owns units u0=m,
// u1=m+128 (all 4 gates = 8 cols {g*256+m, g*256+m+128}) over K-quarter
// q (rows [64q, 64q+64)):
//   rows [64q, 64q+48):   24 h2 x 8 cols = 192 weight regs (as v11)
//   rows [64q+48, 64q+64): LDS wl[(cs*2+t)*512+j], 16 b128 reads (as v11)
// h per thread = its quarter only = 8 b128 reads (HALF of v11's 16) from
// the 36-dword-strided quarter layout (per-instr 4 broadcast addresses
// hit disjoint bank groups -> conflict-free).
// K-combine: DPP xor1+xor2 (pure VALU, bitwise-identical across quad)
// -> redundant local tail for both units (no gate exchange).
// One raw lgkmcnt-only s_barrier/step; parity h; LDS ~129KB -> 1 blk/CU.
// =====================================================================
__global__ __launch_bounds__(512, 1) void lstm_rec19(const float* __restrict__ Whh,
                                                     const float* __restrict__ xp,
                                                     float* __restrict__ obuf) {
  __shared__ uint4 wl[16 * 512];   // 128KB: [(cs*2+t)][j]
  __shared__ uint  hl[2][144];     // h f16-packed, quarter qd at dword 36*qd
  const int d = blockIdx.x;
  const int j = threadIdx.x;
  const int q = j & 3;             // K-quarter
  const int m = j >> 2;            // unit-pair index 0..127
  const float* W   = Whh + (size_t)d * HD * NG;
  const float* xpd = xp + (size_t)d * SQ * NG;

  // ---- LDS weights: rows [64q+48, 64q+64) for the 8 cols ----
#pragma unroll
  for (int cs = 0; cs < 8; ++cs) {
    const int c = (cs >> 1) * 256 + m + (cs & 1) * 128;
#pragma unroll
    for (int t = 0; t < 2; ++t) {
      const int r0 = 64 * q + 48 + 8 * t;
      uint4 v;
      v.x = pk(W[(size_t)(r0 + 0) * NG + c], W[(size_t)(r0 + 1) * NG + c]);
      v.y = pk(W[(size_t)(r0 + 2) * NG + c], W[(size_t)(r0 + 3) * NG + c]);
      v.z = pk(W[(size_t)(r0 + 4) * NG + c], W[(size_t)(r0 + 5) * NG + c]);
      v.w = pk(W[(size_t)(r0 + 6) * NG + c], W[(size_t)(r0 + 7) * NG + c]);
      wl[(cs * 2 + t) * 512 + j] = v;
    }
  }

  // ---- register weights: rows [64q, 64q+48) for the 8 cols ----
  h2 wr[8][24];
#pragma unroll
  for (int cs = 0; cs < 8; ++cs) {
    const int c = (cs >> 1) * 256 + m + (cs & 1) * 128;
    const float* Wc = W + (size_t)(64 * q) * NG + c;
#pragma unroll
    for (int k = 0; k < 24; ++k)
      wr[cs][k] = __builtin_amdgcn_cvt_pkrtz(Wc[(size_t)(2 * k) * NG],
                                             Wc[(size_t)(2 * k + 1) * NG]);
  }

  if (j < 288) ((uint*)hl)[j] = 0u;
  __syncthreads();

  const int fwd = (d == 0) ? 1 : 0;
  int t = fwd ? 0 : SQ - 1;
  const int dt = fwd ? 1 : -1;
  float cc0 = 0.0f, cc1 = 0.0f;
  int p = 0;

  float xc[8], xn[8] = {};
#pragma unroll
  for (int cs = 0; cs < 8; ++cs)
    xc[cs] = xpd[(size_t)t * NG + (cs >> 1) * 256 + m + (cs & 1) * 128];

  for (int step = 0; step < SQ; ++step) {
    // prefetch next xp (global; never drained by the raw barrier)
    if (step + 1 < SQ) {
#pragma unroll
      for (int cs = 0; cs < 8; ++cs)
        xn[cs] = xpd[(size_t)(t + dt) * NG + (cs >> 1) * 256 + m + (cs & 1) * 128];
    }

    // ---- dots over this thread's K-quarter (8 b128 h reads) ----
    const uint4* hb = (const uint4*)&hl[p][q * 36];
    float acc[8] = {};
#pragma unroll
    for (int i = 0; i < 6; ++i) {          // register rows (0..47 of quarter)
      uint4 hq = hb[i];
      h2 h0 = bch2(hq.x), h1 = bch2(hq.y), h2v = bch2(hq.z), h3 = bch2(hq.w);
#pragma unroll
      for (int cs = 0; cs < 8; ++cs) {
        acc[cs] = __builtin_amdgcn_fdot2(wr[cs][4 * i + 0], h0, acc[cs], false);
        acc[cs] = __builtin_amdgcn_fdot2(wr[cs][4 * i + 1], h1, acc[cs], false);
        acc[cs] = __builtin_amdgcn_fdot2(wr[cs][4 * i + 2], h2v, acc[cs], false);
        acc[cs] = __builtin_amdgcn_fdot2(wr[cs][4 * i + 3], h3, acc[cs], false);
      }
    }
#pragma unroll
    for (int tt = 0; tt < 2; ++tt) {       // LDS rows (48..63 of quarter)
      uint4 hq = hb[6 + tt];
      h2 h0 = bch2(hq.x), h1 = bch2(hq.y), h2v = bch2(hq.z), h3 = bch2(hq.w);
#pragma unroll
      for (int cs = 0; cs < 8; ++cs) {
        uint4 wq = wl[(cs * 2 + tt) * 512 + j];
        acc[cs] = __builtin_amdgcn_fdot2(bch2(wq.x), h0, acc[cs], false);
        acc[cs] = __builtin_amdgcn_fdot2(bch2(wq.y), h1, acc[cs], false);
        acc[cs] = __builtin_amdgcn_fdot2(bch2(wq.z), h2v, acc[cs], false);
        acc[cs] = __builtin_amdgcn_fdot2(bch2(wq.w), h3, acc[cs], false);
      }
    }

    // ---- K-combine across the quad (pure VALU, bitwise-uniform) ----
#pragma unroll
    for (int cs = 0; cs < 8; ++cs) {
      acc[cs] += dpp_xor1(acc[cs]);
      acc[cs] += dpp_xor2(acc[cs]);
    }

    // ---- redundant tail in all 4 quad lanes (identical FP) ----
    float iv0 = sigm_f(acc[0] + xc[0]);
    float iv1 = sigm_f(acc[1] + xc[1]);
    float fv0 = sigm_f(acc[2] + xc[2]);
    float fv1 = sigm_f(acc[3] + xc[3]);
    float gv0 = tanh_f(acc[4] + xc[4]);
    float gv1 = tanh_f(acc[5] + xc[5]);
    float ov0 = sigm_f(acc[6] + xc[6]);
    float ov1 = sigm_f(acc[7] + xc[7]);
    cc0 = fv0 * cc0 + iv0 * gv0;
    cc1 = fv1 * cc1 + iv1 * gv1;
    float hv0 = ov0 * tanh_f(cc0);
    float hv1 = ov1 * tanh_f(cc1);

    if (q == 0) {                          // one writer per unit pair
      obuf[(size_t)t * 512 + (d << 8) + m] = hv0;          // fire-and-forget
      obuf[(size_t)t * 512 + (d << 8) + m + 128] = hv1;
      ushort* hp = (ushort*)hl[p ^ 1];
      const int u1 = m + 128;
      const int dw0 = 36 * (m >> 6) + ((m >> 1) & 31);
      const int dw1 = 36 * (u1 >> 6) + ((u1 >> 1) & 31);
      hp[dw0 * 2 + (m & 1)]  = (ushort)(pk(hv0, hv0) & 0xFFFFu);
      hp[dw1 * 2 + (u1 & 1)] = (ushort)(pk(hv1, hv1) & 0xFFFFu);
    }

    // ---- one raw barrier: LDS ordering only, no vmcnt drain ----
    asm volatile("s_waitcnt lgkmcnt(0)" ::: "memory");
    __builtin_amdgcn_s_barrier();
    __builtin_amdgcn_sched_barrier(0);

    p ^= 1;
#pragma unroll
    for (int cs = 0; cs < 8; ++cs) xc[cs] = xn[cs];
    t += dt;
  }
}

// =====================================================================
// classifier head
// =====================================================================
__global__ void cls_k(const float* __restrict__ buf, const float* __restrict__ w1,
                      const float* __restrict__ b1, const float* __restrict__ w2,
                      const float* __restrict__ b2, float* __restrict__ out) {
  __shared__ float feat[512];
  __shared__ float hid[32];
  const int t = threadIdx.x;
  feat[t] = (t < 256) ? buf[(size_t)(SQ - 1) * 512 + t] : buf[t];
  __syncthreads();
  if (t < 32) {
    float a = b1[t];
    for (int k = 0; k < 512; ++k) a = fmaf(feat[k], w1[k * 32 + t], a);
    hid[t] = a;
  }
  __syncthreads();
  if (t < 2) {
    float a = b2[t];
    for (int k = 0; k < 32; ++k) a = fmaf(hid[k], w2[k * 2 + t], a);
    out[t] = a;
  }
}

// =====================================================================
extern "C" void kernel_launch(void* const* d_in, const int* in_sizes, int n_in,
                              void* d_out, int out_size, void* d_ws, size_t ws_size,
                              hipStream_t stream) {
  const float* x     = (const float*)d_in[0];
  const float* w_ih0 = (const float*)d_in[1];
  const float* w_hh0 = (const float*)d_in[2];
  const float* b0    = (const float*)d_in[3];
  const float* w_ih  = (const float*)d_in[4];
  const float* w_hh  = (const float*)d_in[5];
  const float* b     = (const float*)d_in[6];
  const float* w1    = (const float*)d_in[7];
  const float* b1    = (const float*)d_in[8];
  const float* w2    = (const float*)d_in[9];
  const float* b2    = (const float*)d_in[10];

  float* xp   = (float*)d_ws;                       // [2][SQ][NG] = 64MB
  float* bufA = xp + (size_t)2 * SQ * NG;           // [SQ][512]   = 16MB
  float* bufB = bufA + (size_t)SQ * 512;            // [SQ][512]   = 16MB

  const dim3 ggrid(SQ / 64, 32);

  // layer 0
  gemm_xp<<<ggrid, 256, 0, stream>>>(x, 1024, w_ih0, b0, xp);
  lstm_rec19<<<2, 512, 0, stream>>>(w_hh0, xp, bufA);

  // layers 1..4
  float* cur = bufA;
  float* nxt = bufB;
  for (int lyr = 0; lyr < 4; ++lyr) {
    gemm_xp<<<ggrid, 256, 0, stream>>>(cur, 512, w_ih + (size_t)lyr * 2 * 512 * 1024,
                                       b + (size_t)lyr * 2 * 1024, xp);
    lstm_rec19<<<2, 512, 0, stream>>>(w_hh + (size_t)lyr * 2 * 256 * 1024, xp, nxt);
    float* tmp = cur; cur = nxt; nxt = tmp;
  }

  cls_k<<<1, 512, 0, stream>>>(cur, w1, b1, w2, b2, (float*)d_out);
}

// Round 16
// 69017.950 us; speedup vs baseline: 3.1709x; 1.0350x over previous
//
#include <hip/hip_runtime.h>

// ---- problem constants ----
constexpr int SQ = 8192;   // sequence length
constexpr int HD = 256;    // hidden size H
constexpr int NG = 1024;   // 4H (gate width)

typedef __fp16 h2 __attribute__((ext_vector_type(2)));
typedef __fp16 f16x8 __attribute__((ext_vector_type(8)));
typedef float f32x4 __attribute__((ext_vector_type(4)));
typedef unsigned int uint;
typedef unsigned short ushort;

__device__ __forceinline__ float sigm_f(float x) {
  float e = __builtin_amdgcn_exp2f(-1.4426950408889634f * x);
  return __builtin_amdgcn_rcpf(1.0f + e);
}
__device__ __forceinline__ float tanh_f(float x) {
  float e = __builtin_amdgcn_exp2f(2.885390081777927f * x);
  return 1.0f - 2.0f * __builtin_amdgcn_rcpf(1.0f + e);
}
__device__ __forceinline__ h2 bch2(uint v) { return __builtin_bit_cast(h2, v); }
__device__ __forceinline__ uint pk(float a, float b) {
  return __builtin_bit_cast(uint, __builtin_amdgcn_cvt_pkrtz(a, b));
}
__device__ __forceinline__ f16x8 bcf(uint4 v) { return __builtin_bit_cast(f16x8, v); }
// xor lane-bit-0 exchange via DPP quad_perm [1,0,3,2] — pure VALU
__device__ __forceinline__ float dpp_xor1(float x) {
  int v = __builtin_amdgcn_mov_dpp(__builtin_bit_cast(int, x), 0xB1, 0xF, 0xF, true);
  return __builtin_bit_cast(float, v);
}

// =====================================================================
// xp GEMM via MFMA, split-f16 3-term (A_hi*W_hi + A_lo*W_hi + A_hi*W_lo),
// f32 accumulate -> xp error ~1e-6 (no new error source).
// Fragment layouts verified on-HW by round-12's passing run:
//   A(16x32): m=l&15, k=(l>>4)*8+i ; B(32x16): k=(l>>4)*8+i, n=l&15 ;
//   C: row=(l>>4)*4+r, col=l&15.
// Block 256 thr (4 waves), tile M64 x N64, K-chunk 32.
// Wave w computes rows [bm+w*16, +16) x cols [bn, bn+64) (4 n-tiles).
// =====================================================================
__global__ __launch_bounds__(256) void gemm_mfma(const float* __restrict__ A, int K,
                                                 const float* __restrict__ W,
                                                 const float* __restrict__ bias,
                                                 float* __restrict__ out) {
  __shared__ __fp16 Ahi[64][40];   // [m][k], +8 pad f16 per row
  __shared__ __fp16 Alo[64][40];
  __shared__ __fp16 Bhi[64][40];   // TRANSPOSED: [n][k]
  __shared__ __fp16 Blo[64][40];
  const int tid = threadIdx.x;
  const int w   = tid >> 6;
  const int l   = tid & 63;
  const int bm  = blockIdx.x * 64;
  const int d   = blockIdx.y >> 4;
  const int bn  = (blockIdx.y & 15) * 64;
  const float* Wd = W + (size_t)d * K * NG;
  const float* bd = bias + (size_t)d * NG;
  float* outd = out + (size_t)d * SQ * NG;

  // staging roles
  const int ar = tid >> 2, ac8 = (tid & 3) * 8;   // A: 64 rows x 4 col-groups
  const int br = tid >> 3, bc8 = (tid & 7) * 8;   // B: 32 rows x 8 col-groups

  f32x4 c[4] = {{0.f, 0.f, 0.f, 0.f}, {0.f, 0.f, 0.f, 0.f},
                {0.f, 0.f, 0.f, 0.f}, {0.f, 0.f, 0.f, 0.f}};

  for (int kt = 0; kt < K; kt += 32) {
    // ---- load ----
    float4 a0 = *(const float4*)(A + (size_t)(bm + ar) * K + kt + ac8);
    float4 a1 = *(const float4*)(A + (size_t)(bm + ar) * K + kt + ac8 + 4);
    float4 b0 = *(const float4*)(Wd + (size_t)(kt + br) * NG + bn + bc8);
    float4 b1 = *(const float4*)(Wd + (size_t)(kt + br) * NG + bn + bc8 + 4);
    __syncthreads();
    // ---- stage A (hi/lo), one b128 each ----
    {
      float av[8] = {a0.x, a0.y, a0.z, a0.w, a1.x, a1.y, a1.z, a1.w};
      __fp16 hi[8], lo[8];
#pragma unroll
      for (int i = 0; i < 8; ++i) {
        hi[i] = (__fp16)av[i];
        lo[i] = (__fp16)(av[i] - (float)hi[i]);
      }
      *(uint4*)&Ahi[ar][ac8] = *(const uint4*)hi;
      *(uint4*)&Alo[ar][ac8] = *(const uint4*)lo;
    }
    // ---- stage B transposed (hi/lo), u16 scatter ----
    {
      float bv[8] = {b0.x, b0.y, b0.z, b0.w, b1.x, b1.y, b1.z, b1.w};
#pragma unroll
      for (int i = 0; i < 8; ++i) {
        __fp16 hi = (__fp16)bv[i];
        Bhi[bc8 + i][br] = hi;
        Blo[bc8 + i][br] = (__fp16)(bv[i] - (float)hi);
      }
    }
    __syncthreads();
    // ---- compute ----
    f16x8 ah = bcf(*(const uint4*)&Ahi[w * 16 + (l & 15)][(l >> 4) * 8]);
    f16x8 al = bcf(*(const uint4*)&Alo[w * 16 + (l & 15)][(l >> 4) * 8]);
#pragma unroll
    for (int nt = 0; nt < 4; ++nt) {
      f16x8 bh = bcf(*(const uint4*)&Bhi[nt * 16 + (l & 15)][(l >> 4) * 8]);
      f16x8 bl = bcf(*(const uint4*)&Blo[nt * 16 + (l & 15)][(l >> 4) * 8]);
      c[nt] = __builtin_amdgcn_mfma_f32_16x16x32_f16(ah, bh, c[nt], 0, 0, 0);
      c[nt] = __builtin_amdgcn_mfma_f32_16x16x32_f16(al, bh, c[nt], 0, 0, 0);
      c[nt] = __builtin_amdgcn_mfma_f32_16x16x32_f16(ah, bl, c[nt], 0, 0, 0);
    }
  }

  // ---- epilogue: + bias, scattered dword stores (64B segments) ----
#pragma unroll
  for (int nt = 0; nt < 4; ++nt) {
    const int col = bn + nt * 16 + (l & 15);
    const float bb = bd[col];
#pragma unroll
    for (int r = 0; r < 4; ++r) {
      const int row = bm + w * 16 + (l >> 4) * 4 + r;
      outd[(size_t)row * NG + col] = c[nt][r] + bb;
    }
  }
}

// =====================================================================
// LSTM recurrence v23 = v12 with the weight split moved to 208 reg-h2 +
// 12 LDS b128 reads (third point on the 192/16 vs 224/8 axis).
// 512 threads (8 waves). Thread j: unit u=j>>1, K-half s=j&1; owns all
// 4 gate columns of unit u over rows [s*128, s*128+128):
//   rows [s*128, s*128+104):   52 h2 x 4 gates = 208 weight VGPRs
//   rows [s*128+104, s*128+128): LDS wl, flat [(g*3+qq)*512 + j]
// h buffer hl[2][128]: v9/v11-exact. Per step: 16 h-quad broadcasts,
// 208 reg-fdot2 + 48 LDS-fdot2, DPP-xor1 K-combine, redundant pair-lane
// tail, one raw lgkmcnt-only s_barrier. LDS 97KB -> 1 block/CU.
// =====================================================================
__global__ __launch_bounds__(512, 1) void lstm_rec23(const float* __restrict__ Whh,
                                                     const float* __restrict__ xp,
                                                     float* __restrict__ obuf) {
  __shared__ uint4 wl[12 * 512];   // 96KB: [(g*3+qq)][j], j = u*2+s
  __shared__ uint  hl[2][128];     // v9-exact: [parity][dword]
  const int d = blockIdx.x;
  const int j = threadIdx.x;
  const int u = j >> 1;            // unit 0..255
  const int s = j & 1;             // K-half
  const float* W   = Whh + (size_t)d * HD * NG;
  const float* xpd = xp + (size_t)d * SQ * NG;

  // ---- fill LDS weights: rows [ss*128+104, ss*128+128) ----
  for (int idx = j; idx < 12 * 512; idx += 512) {
    const int rem = idx & 511;
    const int uu  = rem >> 1;
    const int ss  = rem & 1;
    const int grp = idx >> 9;        // 0..11
    const int qq  = grp % 3;
    const int g   = grp / 3;
    const int r0  = ss * 128 + 104 + 8 * qq;
    const int c   = g * 256 + uu;
    uint4 v;
    v.x = pk(W[(size_t)(r0 + 0) * NG + c], W[(size_t)(r0 + 1) * NG + c]);
    v.y = pk(W[(size_t)(r0 + 2) * NG + c], W[(size_t)(r0 + 3) * NG + c]);
    v.z = pk(W[(size_t)(r0 + 4) * NG + c], W[(size_t)(r0 + 5) * NG + c]);
    v.w = pk(W[(size_t)(r0 + 6) * NG + c], W[(size_t)(r0 + 7) * NG + c]);
    wl[idx] = v;
  }

  // ---- register weights: rows [s*128, s*128+104) for the 4 gate cols ----
  h2 wr[4][52];
#pragma unroll
  for (int g = 0; g < 4; ++g) {
    const float* Wc = W + (size_t)(s * 128) * NG + g * 256 + u;
#pragma unroll
    for (int k = 0; k < 52; ++k)
      wr[g][k] = __builtin_amdgcn_cvt_pkrtz(Wc[(size_t)(2 * k) * NG],
                                            Wc[(size_t)(2 * k + 1) * NG]);
  }

  if (j < 256) { ((uint*)hl)[j] = 0u; }
  __syncthreads();

  const int fwd = (d == 0) ? 1 : 0;
  int t = fwd ? 0 : SQ - 1;
  const int dt = fwd ? 1 : -1;
  float cc = 0.0f;
  int p = 0;

  float xc[4], xn[4] = {};
#pragma unroll
  for (int g = 0; g < 4; ++g) xc[g] = xpd[(size_t)t * NG + g * 256 + u];

  for (int step = 0; step < SQ; ++step) {
    // prefetch next xp (global; not drained by the raw barrier)
    if (step + 1 < SQ) {
#pragma unroll
      for (int g = 0; g < 4; ++g) xn[g] = xpd[(size_t)(t + dt) * NG + g * 256 + u];
    }

    // ---- dots over this thread's K-half ----
    const uint4* hb = (const uint4*)&hl[p][s * 64];   // 16 quads = 64 h2
    float acc[4] = {0.0f, 0.0f, 0.0f, 0.0f};
#pragma unroll
    for (int q = 0; q < 13; ++q) {          // register rows (0..103 of half)
      uint4 hq = hb[q];
      h2 hx = bch2(hq.x), hy = bch2(hq.y), hz = bch2(hq.z), hw = bch2(hq.w);
#pragma unroll
      for (int g = 0; g < 4; ++g) {
        acc[g] = __builtin_amdgcn_fdot2(wr[g][4 * q + 0], hx, acc[g], false);
        acc[g] = __builtin_amdgcn_fdot2(wr[g][4 * q + 1], hy, acc[g], false);
        acc[g] = __builtin_amdgcn_fdot2(wr[g][4 * q + 2], hz, acc[g], false);
        acc[g] = __builtin_amdgcn_fdot2(wr[g][4 * q + 3], hw, acc[g], false);
      }
    }
#pragma unroll
    for (int qq = 0; qq < 3; ++qq) {        // LDS rows (104..127 of half)
      uint4 hq = hb[13 + qq];
      h2 hx = bch2(hq.x), hy = bch2(hq.y), hz = bch2(hq.z), hw = bch2(hq.w);
#pragma unroll
      for (int g = 0; g < 4; ++g) {
        uint4 wq = wl[(g * 3 + qq) * 512 + j];   // consecutive 16B per lane
        acc[g] = __builtin_amdgcn_fdot2(bch2(wq.x), hx, acc[g], false);
        acc[g] = __builtin_amdgcn_fdot2(bch2(wq.y), hy, acc[g], false);
        acc[g] = __builtin_amdgcn_fdot2(bch2(wq.z), hz, acc[g], false);
        acc[g] = __builtin_amdgcn_fdot2(bch2(wq.w), hw, acc[g], false);
      }
    }

    // ---- K-combine across the lane pair: pure-VALU DPP ----
#pragma unroll
    for (int g = 0; g < 4; ++g) acc[g] += dpp_xor1(acc[g]);

    // ---- redundant full update in both pair-lanes (identical FP) ----
    float iv = sigm_f(acc[0] + xc[0]);
    float fv = sigm_f(acc[1] + xc[1]);
    float gv = tanh_f(acc[2] + xc[2]);
    float ov = sigm_f(acc[3] + xc[3]);
    cc = fv * cc + iv * gv;
    float hv = ov * tanh_f(cc);

    if (s == 0) {
      obuf[(size_t)t * 512 + (d << 8) + u] = hv;     // fire-and-forget
      ((ushort*)hl[p ^ 1])[u] = (ushort)(pk(hv, hv) & 0xFFFFu);
    }

    // ---- one raw barrier: LDS ordering only, no vmcnt drain ----
    asm volatile("s_waitcnt lgkmcnt(0)" ::: "memory");
    __builtin_amdgcn_s_barrier();
    __builtin_amdgcn_sched_barrier(0);

    p ^= 1;
#pragma unroll
    for (int g = 0; g < 4; ++g) xc[g] = xn[g];
    t += dt;
  }
}

// =====================================================================
// classifier head
// =====================================================================
__global__ void cls_k(const float* __restrict__ buf, const float* __restrict__ w1,
                      const float* __restrict__ b1, const float* __restrict__ w2,
                      const float* __restrict__ b2, float* __restrict__ out) {
  __shared__ float feat[512];
  __shared__ float hid[32];
  const int t = threadIdx.x;
  feat[t] = (t < 256) ? buf[(size_t)(SQ - 1) * 512 + t] : buf[t];
  __syncthreads();
  if (t < 32) {
    float a = b1[t];
    for (int k = 0; k < 512; ++k) a = fmaf(feat[k], w1[k * 32 + t], a);
    hid[t] = a;
  }
  __syncthreads();
  if (t < 2) {
    float a = b2[t];
    for (int k = 0; k < 32; ++k) a = fmaf(hid[k], w2[k * 2 + t], a);
    out[t] = a;
  }
}

// =====================================================================
extern "C" void kernel_launch(void* const* d_in, const int* in_sizes, int n_in,
                              void* d_out, int out_size, void* d_ws, size_t ws_size,
                              hipStream_t stream) {
  const float* x     = (const float*)d_in[0];
  const float* w_ih0 = (const float*)d_in[1];
  const float* w_hh0 = (const float*)d_in[2];
  const float* b0    = (const float*)d_in[3];
  const float* w_ih  = (const float*)d_in[4];
  const float* w_hh  = (const float*)d_in[5];
  const float* b     = (const float*)d_in[6];
  const float* w1    = (const float*)d_in[7];
  const float* b1    = (const float*)d_in[8];
  const float* w2    = (const float*)d_in[9];
  const float* b2    = (const float*)d_in[10];

  float* xp   = (float*)d_ws;                       // [2][SQ][NG] = 64MB
  float* bufA = xp + (size_t)2 * SQ * NG;           // [SQ][512]   = 16MB
  float* bufB = bufA + (size_t)SQ * 512;            // [SQ][512]   = 16MB

  const dim3 ggrid(SQ / 64, 32);

  // layer 0
  gemm_mfma<<<ggrid, 256, 0, stream>>>(x, 1024, w_ih0, b0, xp);
  lstm_rec23<<<2, 512, 0, stream>>>(w_hh0, xp, bufA);

  // layers 1..4
  float* cur = bufA;
  float* nxt = bufB;
  for (int lyr = 0; lyr < 4; ++lyr) {
    gemm_mfma<<<ggrid, 256, 0, stream>>>(cur, 512, w_ih + (size_t)lyr * 2 * 512 * 1024,
                                         b + (size_t)lyr * 2 * 1024, xp);
    lstm_rec23<<<2, 512, 0, stream>>>(w_hh + (size_t)lyr * 2 * 256 * 1024, xp, nxt);
    float* tmp = cur; cur = nxt; nxt = tmp;
  }

  cls_k<<<1, 512, 0, stream>>>(cur, w1, b1, w2, b2, (float*)d_out);
}

// Round 17
// 63247.839 us; speedup vs baseline: 3.4602x; 1.0912x over previous
//
#include <hip/hip_runtime.h>

// ---- problem constants ----
constexpr int SQ = 8192;   // sequence length
constexpr int HD = 256;    // hidden size H
constexpr int NG = 1024;   // 4H (gate width)

typedef __fp16 h2 __attribute__((ext_vector_type(2)));
typedef __fp16 f16x8 __attribute__((ext_vector_type(8)));
typedef float f32x4 __attribute__((ext_vector_type(4)));
typedef unsigned int uint;
typedef unsigned short ushort;

__device__ __forceinline__ float sigm_f(float x) {
  float e = __builtin_amdgcn_exp2f(-1.4426950408889634f * x);
  return __builtin_amdgcn_rcpf(1.0f + e);
}
__device__ __forceinline__ float tanh_f(float x) {
  float e = __builtin_amdgcn_exp2f(2.885390081777927f * x);
  return 1.0f - 2.0f * __builtin_amdgcn_rcpf(1.0f + e);
}
__device__ __forceinline__ h2 bch2(uint v) { return __builtin_bit_cast(h2, v); }
__device__ __forceinline__ uint pk(float a, float b) {
  return __builtin_bit_cast(uint, __builtin_amdgcn_cvt_pkrtz(a, b));
}
__device__ __forceinline__ f16x8 bcf(uint4 v) { return __builtin_bit_cast(f16x8, v); }
// xor lane-bit-0 exchange via DPP quad_perm [1,0,3,2] — pure VALU
__device__ __forceinline__ float dpp_xor1(float x) {
  int v = __builtin_amdgcn_mov_dpp(__builtin_bit_cast(int, x), 0xB1, 0xF, 0xF, true);
  return __builtin_bit_cast(float, v);
}

// =====================================================================
// xp GEMM via MFMA, split-f16 3-term (A_hi*W_hi + A_lo*W_hi + A_hi*W_lo),
// f32 accumulate -> xp error ~1e-6. Verified round 16 (absmax 0 vs ref).
// Fragment layouts HW-verified by round-12's passing run.
// Block 256 thr (4 waves), tile M64 x N64, K-chunk 32.
// =====================================================================
__global__ __launch_bounds__(256) void gemm_mfma(const float* __restrict__ A, int K,
                                                 const float* __restrict__ W,
                                                 const float* __restrict__ bias,
                                                 float* __restrict__ out) {
  __shared__ __fp16 Ahi[64][40];   // [m][k], +8 pad f16 per row
  __shared__ __fp16 Alo[64][40];
  __shared__ __fp16 Bhi[64][40];   // TRANSPOSED: [n][k]
  __shared__ __fp16 Blo[64][40];
  const int tid = threadIdx.x;
  const int w   = tid >> 6;
  const int l   = tid & 63;
  const int bm  = blockIdx.x * 64;
  const int d   = blockIdx.y >> 4;
  const int bn  = (blockIdx.y & 15) * 64;
  const float* Wd = W + (size_t)d * K * NG;
  const float* bd = bias + (size_t)d * NG;
  float* outd = out + (size_t)d * SQ * NG;

  const int ar = tid >> 2, ac8 = (tid & 3) * 8;   // A: 64 rows x 4 col-groups
  const int br = tid >> 3, bc8 = (tid & 7) * 8;   // B: 32 rows x 8 col-groups

  f32x4 c[4] = {{0.f, 0.f, 0.f, 0.f}, {0.f, 0.f, 0.f, 0.f},
                {0.f, 0.f, 0.f, 0.f}, {0.f, 0.f, 0.f, 0.f}};

  for (int kt = 0; kt < K; kt += 32) {
    float4 a0 = *(const float4*)(A + (size_t)(bm + ar) * K + kt + ac8);
    float4 a1 = *(const float4*)(A + (size_t)(bm + ar) * K + kt + ac8 + 4);
    float4 b0 = *(const float4*)(Wd + (size_t)(kt + br) * NG + bn + bc8);
    float4 b1 = *(const float4*)(Wd + (size_t)(kt + br) * NG + bn + bc8 + 4);
    __syncthreads();
    {
      float av[8] = {a0.x, a0.y, a0.z, a0.w, a1.x, a1.y, a1.z, a1.w};
      __fp16 hi[8], lo[8];
#pragma unroll
      for (int i = 0; i < 8; ++i) {
        hi[i] = (__fp16)av[i];
        lo[i] = (__fp16)(av[i] - (float)hi[i]);
      }
      *(uint4*)&Ahi[ar][ac8] = *(const uint4*)hi;
      *(uint4*)&Alo[ar][ac8] = *(const uint4*)lo;
    }
    {
      float bv[8] = {b0.x, b0.y, b0.z, b0.w, b1.x, b1.y, b1.z, b1.w};
#pragma unroll
      for (int i = 0; i < 8; ++i) {
        __fp16 hi = (__fp16)bv[i];
        Bhi[bc8 + i][br] = hi;
        Blo[bc8 + i][br] = (__fp16)(bv[i] - (float)hi);
      }
    }
    __syncthreads();
    f16x8 ah = bcf(*(const uint4*)&Ahi[w * 16 + (l & 15)][(l >> 4) * 8]);
    f16x8 al = bcf(*(const uint4*)&Alo[w * 16 + (l & 15)][(l >> 4) * 8]);
#pragma unroll
    for (int nt = 0; nt < 4; ++nt) {
      f16x8 bh = bcf(*(const uint4*)&Bhi[nt * 16 + (l & 15)][(l >> 4) * 8]);
      f16x8 bl = bcf(*(const uint4*)&Blo[nt * 16 + (l & 15)][(l >> 4) * 8]);
      c[nt] = __builtin_amdgcn_mfma_f32_16x16x32_f16(ah, bh, c[nt], 0, 0, 0);
      c[nt] = __builtin_amdgcn_mfma_f32_16x16x32_f16(al, bh, c[nt], 0, 0, 0);
      c[nt] = __builtin_amdgcn_mfma_f32_16x16x32_f16(ah, bl, c[nt], 0, 0, 0);
    }
  }

#pragma unroll
  for (int nt = 0; nt < 4; ++nt) {
    const int col = bn + nt * 16 + (l & 15);
    const float bb = bd[col];
#pragma unroll
    for (int r = 0; r < 4; ++r) {
      const int row = bm + w * 16 + (l >> 4) * 4 + r;
      outd[(size_t)row * NG + col] = c[nt][r] + bb;
    }
  }
}

// =====================================================================
// LSTM recurrence v12 (the 11.94 ms champion, rounds 10/11) — byte-exact.
// 512 threads (8 waves). Thread j: unit u=j>>1, K-half s=j&1; owns all
// 4 gate columns of unit u over rows [s*128, s*128+128):
//   rows [s*128, s*128+96):   48 h2 x 4 gates = 192 weight VGPRs
//   rows [s*128+96, s*128+128): LDS wl, flat [(g*4+qq)*512 + j]
// h buffer hl[2][128]. Per step: 16 h-quad broadcasts, 192 reg-fdot2 +
// 64 LDS-fdot2, DPP-xor1 K-combine, redundant pair-lane tail, one raw
// lgkmcnt-only s_barrier. LDS 129KB -> 1 block/CU.
// =====================================================================
__global__ __launch_bounds__(512, 1) void lstm_rec12(const float* __restrict__ Whh,
                                                     const float* __restrict__ xp,
                                                     float* __restrict__ obuf) {
  __shared__ uint4 wl[16 * 512];   // 128KB: [(g*4+qq)][j], j = u*2+s
  __shared__ uint  hl[2][128];     // [parity][dword]
  const int d = blockIdx.x;
  const int j = threadIdx.x;
  const int u = j >> 1;            // unit 0..255
  const int s = j & 1;             // K-half
  const float* W   = Whh + (size_t)d * HD * NG;
  const float* xpd = xp + (size_t)d * SQ * NG;

  // ---- fill LDS weights: rows [ss*128+96, ss*128+128) ----
  for (int idx = j; idx < 16 * 512; idx += 512) {
    const int rem = idx & 511;
    const int uu  = rem >> 1;
    const int ss  = rem & 1;
    const int qq  = (idx >> 9) & 3;
    const int g   = idx >> 11;
    const int r0  = ss * 128 + 96 + 8 * qq;
    const int c   = g * 256 + uu;
    uint4 v;
    v.x = pk(W[(size_t)(r0 + 0) * NG + c], W[(size_t)(r0 + 1) * NG + c]);
    v.y = pk(W[(size_t)(r0 + 2) * NG + c], W[(size_t)(r0 + 3) * NG + c]);
    v.z = pk(W[(size_t)(r0 + 4) * NG + c], W[(size_t)(r0 + 5) * NG + c]);
    v.w = pk(W[(size_t)(r0 + 6) * NG + c], W[(size_t)(r0 + 7) * NG + c]);
    wl[idx] = v;
  }

  // ---- register weights: rows [s*128, s*128+96) for the 4 gate cols ----
  h2 wr[4][48];
#pragma unroll
  for (int g = 0; g < 4; ++g) {
    const float* Wc = W + (size_t)(s * 128) * NG + g * 256 + u;
#pragma unroll
    for (int k = 0; k < 48; ++k)
      wr[g][k] = __builtin_amdgcn_cvt_pkrtz(Wc[(size_t)(2 * k) * NG],
                                            Wc[(size_t)(2 * k + 1) * NG]);
  }

  if (j < 256) { ((uint*)hl)[j] = 0u; }
  __syncthreads();

  const int fwd = (d == 0) ? 1 : 0;
  int t = fwd ? 0 : SQ - 1;
  const int dt = fwd ? 1 : -1;
  float cc = 0.0f;
  int p = 0;

  float xc[4], xn[4] = {};
#pragma unroll
  for (int g = 0; g < 4; ++g) xc[g] = xpd[(size_t)t * NG + g * 256 + u];

  for (int step = 0; step < SQ; ++step) {
    // prefetch next xp (global; not drained by the raw barrier)
    if (step + 1 < SQ) {
#pragma unroll
      for (int g = 0; g < 4; ++g) xn[g] = xpd[(size_t)(t + dt) * NG + g * 256 + u];
    }

    // ---- dots over this thread's K-half ----
    const uint4* hb = (const uint4*)&hl[p][s * 64];   // 16 quads = 64 h2
    float acc[4] = {0.0f, 0.0f, 0.0f, 0.0f};
#pragma unroll
    for (int q = 0; q < 12; ++q) {          // register rows (0..95 of half)
      uint4 hq = hb[q];
      h2 hx = bch2(hq.x), hy = bch2(hq.y), hz = bch2(hq.z), hw = bch2(hq.w);
#pragma unroll
      for (int g = 0; g < 4; ++g) {
        acc[g] = __builtin_amdgcn_fdot2(wr[g][4 * q + 0], hx, acc[g], false);
        acc[g] = __builtin_amdgcn_fdot2(wr[g][4 * q + 1], hy, acc[g], false);
        acc[g] = __builtin_amdgcn_fdot2(wr[g][4 * q + 2], hz, acc[g], false);
        acc[g] = __builtin_amdgcn_fdot2(wr[g][4 * q + 3], hw, acc[g], false);
      }
    }
#pragma unroll
    for (int qq = 0; qq < 4; ++qq) {        // LDS rows (96..127 of half)
      uint4 hq = hb[12 + qq];
      h2 hx = bch2(hq.x), hy = bch2(hq.y), hz = bch2(hq.z), hw = bch2(hq.w);
#pragma unroll
      for (int g = 0; g < 4; ++g) {
        uint4 wq = wl[(g * 4 + qq) * 512 + j];   // consecutive 16B per lane
        acc[g] = __builtin_amdgcn_fdot2(bch2(wq.x), hx, acc[g], false);
        acc[g] = __builtin_amdgcn_fdot2(bch2(wq.y), hy, acc[g], false);
        acc[g] = __builtin_amdgcn_fdot2(bch2(wq.z), hz, acc[g], false);
        acc[g] = __builtin_amdgcn_fdot2(bch2(wq.w), hw, acc[g], false);
      }
    }

    // ---- K-combine across the lane pair: pure-VALU DPP ----
#pragma unroll
    for (int g = 0; g < 4; ++g) acc[g] += dpp_xor1(acc[g]);

    // ---- redundant full update in both pair-lanes (identical FP) ----
    float iv = sigm_f(acc[0] + xc[0]);
    float fv = sigm_f(acc[1] + xc[1]);
    float gv = tanh_f(acc[2] + xc[2]);
    float ov = sigm_f(acc[3] + xc[3]);
    cc = fv * cc + iv * gv;
    float hv = ov * tanh_f(cc);

    if (s == 0) {
      obuf[(size_t)t * 512 + (d << 8) + u] = hv;     // fire-and-forget
      ((ushort*)hl[p ^ 1])[u] = (ushort)(pk(hv, hv) & 0xFFFFu);
    }

    // ---- one raw barrier: LDS ordering only, no vmcnt drain ----
    asm volatile("s_waitcnt lgkmcnt(0)" ::: "memory");
    __builtin_amdgcn_s_barrier();
    __builtin_amdgcn_sched_barrier(0);

    p ^= 1;
#pragma unroll
    for (int g = 0; g < 4; ++g) xc[g] = xn[g];
    t += dt;
  }
}

// =====================================================================
// classifier head
// =====================================================================
__global__ void cls_k(const float* __restrict__ buf, const float* __restrict__ w1,
                      const float* __restrict__ b1, const float* __restrict__ w2,
                      const float* __restrict__ b2, float* __restrict__ out) {
  __shared__ float feat[512];
  __shared__ float hid[32];
  const int t = threadIdx.x;
  feat[t] = (t < 256) ? buf[(size_t)(SQ - 1) * 512 + t] : buf[t];
  __syncthreads();
  if (t < 32) {
    float a = b1[t];
    for (int k = 0; k < 512; ++k) a = fmaf(feat[k], w1[k * 32 + t], a);
    hid[t] = a;
  }
  __syncthreads();
  if (t < 2) {
    float a = b2[t];
    for (int k = 0; k < 32; ++k) a = fmaf(hid[k], w2[k * 2 + t], a);
    out[t] = a;
  }
}

// =====================================================================
extern "C" void kernel_launch(void* const* d_in, const int* in_sizes, int n_in,
                              void* d_out, int out_size, void* d_ws, size_t ws_size,
                              hipStream_t stream) {
  const float* x     = (const float*)d_in[0];
  const float* w_ih0 = (const float*)d_in[1];
  const float* w_hh0 = (const float*)d_in[2];
  const float* b0    = (const float*)d_in[3];
  const float* w_ih  = (const float*)d_in[4];
  const float* w_hh  = (const float*)d_in[5];
  const float* b     = (const float*)d_in[6];
  const float* w1    = (const float*)d_in[7];
  const float* b1    = (const float*)d_in[8];
  const float* w2    = (const float*)d_in[9];
  const float* b2    = (const float*)d_in[10];

  float* xp   = (float*)d_ws;                       // [2][SQ][NG] = 64MB
  float* bufA = xp + (size_t)2 * SQ * NG;           // [SQ][512]   = 16MB
  float* bufB = bufA + (size_t)SQ * 512;            // [SQ][512]   = 16MB

  const dim3 ggrid(SQ / 64, 32);

  // layer 0
  gemm_mfma<<<ggrid, 256, 0, stream>>>(x, 1024, w_ih0, b0, xp);
  lstm_rec12<<<2, 512, 0, stream>>>(w_hh0, xp, bufA);

  // layers 1..4
  float* cur = bufA;
  float* nxt = bufB;
  for (int lyr = 0; lyr < 4; ++lyr) {
    gemm_mfma<<<ggrid, 256, 0, stream>>>(cur, 512, w_ih + (size_t)lyr * 2 * 512 * 1024,
                                         b + (size_t)lyr * 2 * 1024, xp);
    lstm_rec12<<<2, 512, 0, stream>>>(w_hh + (size_t)lyr * 2 * 256 * 1024, xp, nxt);
    float* tmp = cur; cur = nxt; nxt = tmp;
  }

  cls_k<<<1, 512, 0, stream>>>(cur, w1, b1, w2, b2, (float*)d_out);
}